// Round 11
// baseline (284.664 us; speedup 1.0000x reference)
//
#include <hip/hip_runtime.h>
#include <hip/hip_bf16.h>

#define M_DIM 4096
#define N_DIM 4096
#define K_DIM 4096

typedef __attribute__((ext_vector_type(8))) __bf16 bf16x8;
typedef __attribute__((ext_vector_type(8))) short short8;
typedef __attribute__((ext_vector_type(8))) unsigned short ushort8;
typedef __attribute__((ext_vector_type(4))) float f32x4;

// async global->LDS, 16B/lane (m104: dest = wave-uniform base + lane*16)
__device__ __forceinline__ void gload_lds16(const void* g, void* l) {
    __builtin_amdgcn_global_load_lds(
        (const __attribute__((address_space(1))) void*)g,
        (__attribute__((address_space(3))) void*)l,
        16, 0, 0);
}

__device__ __forceinline__ bf16x8 ld8(const unsigned short* p) {
    short8 r = *reinterpret_cast<const short8*>(p);
    return __builtin_bit_cast(bf16x8, r);
}

// ---------------------------------------------------------------------------
// fused fp32->bf16 conversion: x (pruned) and w (unpruned) in ONE launch
// ---------------------------------------------------------------------------
__global__ void prune_cvt2(const float* __restrict__ x,
                           const float* __restrict__ w,
                           unsigned short* __restrict__ xb,
                           unsigned short* __restrict__ wb,
                           const float* __restrict__ thrp, int n8) {
    const float thr = thrp[0];
    const int stride = gridDim.x * blockDim.x;
    const int total = 2 * n8;
    for (int idx = blockIdx.x * blockDim.x + threadIdx.x; idx < total; idx += stride) {
        const bool isx = idx < n8;
        const int j = isx ? idx : idx - n8;
        const float* src = isx ? x : w;
        unsigned short* dst = isx ? xb : wb;
        const float te = isx ? thr : -1.0f;   // |v| > -1 always true -> keep all
        const float4* p = reinterpret_cast<const float4*>(src) + 2 * (size_t)j;
        float4 v0 = p[0];
        float4 v1 = p[1];
        float v[8] = {v0.x, v0.y, v0.z, v0.w, v1.x, v1.y, v1.z, v1.w};
        ushort8 o;
#pragma unroll
        for (int e = 0; e < 8; ++e) {
            float f = v[e];
            f = (fabsf(f) > te) ? f : 0.0f;   // prune in fp32 (exact predicate)
            __hip_bfloat16 hh = __float2bfloat16(f);
            o[e] = *reinterpret_cast<unsigned short*>(&hh);
        }
        *reinterpret_cast<ushort8*>(dst + 8 * (size_t)j) = o;
    }
}

// ---------------------------------------------------------------------------
// C = A * B^T, 256x256 tile, BK=64, FOUR waves (2x2), per-wave 128x128 output,
// 16x16x32 MFMA, acc[8][8] (256 VGPR, 1 wave/SIMD, 512-VGPR class).
// Rationale: square per-wave tile cuts LDS frag reads to 0.25 reads/MFMA
// (vs 0.375 for 8-wave 128x64) -> LDS-engine floor drops ~33%.
//
// Phases = m-pairs. Per wave per tile: 16 ds_read (A) + 16 ds_read (B) = 32.
// All reads are >=1-phase-ahead of their consuming MFMA (R6 discipline):
//   ph3(t-1) pre-reads m0-1(t) [p-set] and ALL B(t) frags [reg-dbuf].
// Staging (16 gload/thread/tile): ph0: SB'(t+1)x8 + SA'(t+1){0,4};
//   ph1: SA'{1,5}; ph2: SA'{2,6}; ph3: SA'{3,7}.
// Barrier+wait only at end-ph1 and end-ph3, both vmcnt(2) (FIFO-verified):
//   W1 lands [A(t){3,7}, B(t+1)x8, A(t+1){0,4}] -> ph2 reads m6-7, ph3
//     pre-reads B(t+1)+A(t+1)m0-1 (all cross-wave reads are post-barrier).
//   W3 lands [A(t+1){1,5},{2,6}] -> next ph0/ph1 reads.
// A-load j covers rows [32j,+32): wave wr's m-pair q needs load 4*wr+q.
//
// LDS per buffer: A[256][64] (32KB), B[256][64] (32KB), x2 dbuf = 128KB.
// Slot-swizzle: element(row, col c) at row*64 + 8*((c>>3) ^ (row&7)) + (c&7).
// ---------------------------------------------------------------------------
__global__ __launch_bounds__(256, 1) void gemm_bigacc(
        const unsigned short* __restrict__ A,
        const unsigned short* __restrict__ B,
        float* __restrict__ C) {
    __shared__ __align__(16) unsigned short lds[65536];  // 128 KB

    const int tid  = threadIdx.x;
    const int lane = tid & 63;
    const int wid  = tid >> 6;   // 0..3
    const int wr   = wid >> 1;   // 0..1 : 128-row strip
    const int wc   = wid & 1;    // 0..1 : 128-col strip

    // XCD-aware bijective swizzle (256 blocks / 8 XCDs)
    const int bid = blockIdx.x;
    const int swz = (bid & 7) * 32 + (bid >> 3);
    const int bm = (swz >> 4) * 256;
    const int bn = (swz & 15) * 256;

    // cooperative staging: all 256 threads per load; load j = rows [32j,+32)
    const int g = tid;
    const int srow = g >> 3;                              // 0..31 within a load
    const int scol = 8 * ((g & 7) ^ (srow & 7));          // pre-swizzled source col
    const unsigned short* Asrc = A + (size_t)(bm + srow) * K_DIM + scol;
    const unsigned short* Bsrc = B + (size_t)(bn + srow) * K_DIM + scol;
    const int dstE = g * 8;

#define SA(dstb, j, kg) gload_lds16(Asrc + (size_t)(32*(j))*K_DIM + (kg), (dstb) + 2048*(j) + dstE)
#define SB(dstb, j, kg) gload_lds16(Bsrc + (size_t)(32*(j))*K_DIM + (kg), (dstb) + 2048*(j) + dstE)

    // fragment read offsets (row&7 == fr&7 -> swizzle slot is thread-constant)
    const int fr  = lane & 15;
    const int kq4 = lane >> 4;
    const int rowOffA = (wr * 128 + fr) * 64;
    const int rowOffB = (wc * 128 + fr) * 64;
    const int sk0 = 8 * ((kq4    ) ^ (fr & 7));
    const int sk1 = 8 * ((kq4 + 4) ^ (fr & 7));

    f32x4 acc[8][8] = {};

    // B fragment register sets, double-buffered across the unrolled t-loop
    bf16x8 bfE[8][2], bfO[8][2];

    // one phase: m-pair q (2 m-frags x 8 n x 2 kk = 32 MFMA)
#define MFMA32(q, BF, A00, A10, A01, A11)                                                          \
    __builtin_amdgcn_s_setprio(1);                                                                 \
    _Pragma("unroll")                                                                              \
    for (int n = 0; n < 8; ++n) {                                                                  \
        acc[2*(q)][n]   = __builtin_amdgcn_mfma_f32_16x16x32_bf16(A00, BF[n][0], acc[2*(q)][n], 0, 0, 0);   \
        acc[2*(q)+1][n] = __builtin_amdgcn_mfma_f32_16x16x32_bf16(A10, BF[n][0], acc[2*(q)+1][n], 0, 0, 0); \
    }                                                                                              \
    _Pragma("unroll")                                                                              \
    for (int n = 0; n < 8; ++n) {                                                                  \
        acc[2*(q)][n]   = __builtin_amdgcn_mfma_f32_16x16x32_bf16(A01, BF[n][1], acc[2*(q)][n], 0, 0, 0);   \
        acc[2*(q)+1][n] = __builtin_amdgcn_mfma_f32_16x16x32_bf16(A11, BF[n][1], acc[2*(q)+1][n], 0, 0, 0); \
    }                                                                                              \
    __builtin_amdgcn_s_setprio(0);

    // A-frag LDS offsets: wave wr, m-frag m -> rowOffA + m*1024 (+ sk)
#define TILE_BODY(Ab, Bb, AbN, BbN, BFC, BFN, kn)                                                  \
    {                                                                                              \
        /* ph0: MFMA m0-1 (p-set); read m2-3 (q-set); stage SB'x8 + SA'{0,4} */                    \
        bf16x8 q00 = ld8((Ab) + rowOffA + 2 * 1024 + sk0);                                         \
        bf16x8 q10 = ld8((Ab) + rowOffA + 3 * 1024 + sk0);                                         \
        bf16x8 q01 = ld8((Ab) + rowOffA + 2 * 1024 + sk1);                                         \
        bf16x8 q11 = ld8((Ab) + rowOffA + 3 * 1024 + sk1);                                         \
        SB((BbN), 0, (kn)); SB((BbN), 1, (kn)); SB((BbN), 2, (kn)); SB((BbN), 3, (kn));            \
        SB((BbN), 4, (kn)); SB((BbN), 5, (kn)); SB((BbN), 6, (kn)); SB((BbN), 7, (kn));            \
        SA((AbN), 0, (kn)); SA((AbN), 4, (kn));                                                    \
        MFMA32(0, BFC, p00, p10, p01, p11);                                                        \
        /* ph1: MFMA m2-3 (q); read m4-5 (r); stage SA'{1,5} */                                    \
        bf16x8 r00 = ld8((Ab) + rowOffA + 4 * 1024 + sk0);                                         \
        bf16x8 r10 = ld8((Ab) + rowOffA + 5 * 1024 + sk0);                                         \
        bf16x8 r01 = ld8((Ab) + rowOffA + 4 * 1024 + sk1);                                         \
        bf16x8 r11 = ld8((Ab) + rowOffA + 5 * 1024 + sk1);                                         \
        SA((AbN), 1, (kn)); SA((AbN), 5, (kn));                                                    \
        MFMA32(1, BFC, q00, q10, q01, q11);                                                        \
        asm volatile("s_waitcnt vmcnt(2)" ::: "memory");                                           \
        asm volatile("s_barrier" ::: "memory");                                                    \
        /* ph2: MFMA m4-5 (r); read m6-7 (s); stage SA'{2,6} */                                    \
        bf16x8 s00 = ld8((Ab) + rowOffA + 6 * 1024 + sk0);                                         \
        bf16x8 s10 = ld8((Ab) + rowOffA + 7 * 1024 + sk0);                                         \
        bf16x8 s01 = ld8((Ab) + rowOffA + 6 * 1024 + sk1);                                         \
        bf16x8 s11 = ld8((Ab) + rowOffA + 7 * 1024 + sk1);                                         \
        SA((AbN), 2, (kn)); SA((AbN), 6, (kn));                                                    \
        MFMA32(2, BFC, r00, r10, r01, r11);                                                        \
        /* ph3: MFMA m6-7 (s); pre-read A(t+1) m0-1 + ALL B(t+1)->BFN; stage SA'{3,7} */           \
        p00 = ld8((AbN) + rowOffA + 0 * 1024 + sk0);                                               \
        p10 = ld8((AbN) + rowOffA + 1 * 1024 + sk0);                                               \
        p01 = ld8((AbN) + rowOffA + 0 * 1024 + sk1);                                               \
        p11 = ld8((AbN) + rowOffA + 1 * 1024 + sk1);                                               \
        _Pragma("unroll")                                                                          \
        for (int n = 0; n < 8; ++n) {                                                              \
            BFN[n][0] = ld8((BbN) + rowOffB + n * 1024 + sk0);                                     \
            BFN[n][1] = ld8((BbN) + rowOffB + n * 1024 + sk1);                                     \
        }                                                                                          \
        SA((AbN), 3, (kn)); SA((AbN), 7, (kn));                                                    \
        MFMA32(3, BFC, s00, s10, s01, s11);                                                        \
        asm volatile("s_waitcnt vmcnt(2)" ::: "memory");                                           \
        asm volatile("s_barrier" ::: "memory");                                                    \
    }

    // compile-time buffer bases
    unsigned short* A0 = lds;
    unsigned short* A1 = lds + 16384;
    unsigned short* B0 = lds + 32768;
    unsigned short* B1 = lds + 49152;

    // ---- prologue: stage tile0 (B x8, then A in order 0,4,1,5,2,6,3,7);
    // vmcnt(2) leaves [A(0)3, A(0)7] = the steady invariant.
    SB(B0, 0, 0); SB(B0, 1, 0); SB(B0, 2, 0); SB(B0, 3, 0);
    SB(B0, 4, 0); SB(B0, 5, 0); SB(B0, 6, 0); SB(B0, 7, 0);
    SA(A0, 0, 0); SA(A0, 4, 0); SA(A0, 1, 0); SA(A0, 5, 0);
    SA(A0, 2, 0); SA(A0, 6, 0); SA(A0, 3, 0); SA(A0, 7, 0);
    asm volatile("s_waitcnt vmcnt(2)" ::: "memory");
    asm volatile("s_barrier" ::: "memory");

    // pre-read tile-0 working set: A m0-1 (p-set) + all B(0) frags -> bfE
    bf16x8 p00 = ld8(A0 + rowOffA + 0 * 1024 + sk0);
    bf16x8 p10 = ld8(A0 + rowOffA + 1 * 1024 + sk0);
    bf16x8 p01 = ld8(A0 + rowOffA + 0 * 1024 + sk1);
    bf16x8 p11 = ld8(A0 + rowOffA + 1 * 1024 + sk1);
#pragma unroll
    for (int n = 0; n < 8; ++n) {
        bfE[n][0] = ld8(B0 + rowOffB + n * 1024 + sk0);
        bfE[n][1] = ld8(B0 + rowOffB + n * 1024 + sk1);
    }

    for (int t = 0; t < 64; t += 2) {
        const int kn0 = (t + 1) * 64;                     // t+1 <= 63, never clamps
        const int kn1 = (t + 2 < 64 ? t + 2 : 63) * 64;   // clamp: tail stages dead
        // even tile: read buf0 + bfE; stage tile t+1 -> buf1; pre-read -> bfO
        TILE_BODY(A0, B0, A1, B1, bfE, bfO, kn0);
        // odd tile:  read buf1 + bfO; stage tile t+2 -> buf0; pre-read -> bfE
        TILE_BODY(A1, B1, A0, B0, bfO, bfE, kn1);
    }

    asm volatile("s_waitcnt vmcnt(0)" ::: "memory");  // drain dead tail stages

    // C/D layout (m89): col = lane&15, row = (lane>>4)*4 + j
    const int crow = bm + wr * 128 + kq4 * 4;
    const int ccol = bn + wc * 128 + fr;
#pragma unroll
    for (int m = 0; m < 8; ++m)
#pragma unroll
        for (int n = 0; n < 8; ++n)
#pragma unroll
            for (int j = 0; j < 4; ++j)
                C[(size_t)(crow + m * 16 + j) * N_DIM + ccol + n * 16] = acc[m][n][j];
}

// ---------------------------------------------------------------------------
// fp32 fallback (only if ws too small)
// ---------------------------------------------------------------------------
__global__ void gemm_f32_fallback(const float* __restrict__ A,
                                  const float* __restrict__ B,
                                  float* __restrict__ C,
                                  const float* __restrict__ thrp) {
    __shared__ float As[32][33];
    __shared__ float Bs[32][33];
    const float thr = thrp[0];
    const int tx = threadIdx.x, ty = threadIdx.y;
    const int row = blockIdx.y * 32 + ty;
    float acc = 0.0f;
    for (int k0 = 0; k0 < K_DIM; k0 += 32) {
        float a = A[(size_t)row * K_DIM + k0 + tx];
        As[ty][tx] = (fabsf(a) > thr) ? a : 0.0f;
        Bs[ty][tx] = B[(size_t)(blockIdx.x * 32 + ty) * K_DIM + k0 + tx];
        __syncthreads();
#pragma unroll 8
        for (int kk = 0; kk < 32; ++kk)
            acc += As[ty][kk] * Bs[tx][kk];
        __syncthreads();
    }
    C[(size_t)row * N_DIM + blockIdx.x * 32 + tx] = acc;
}

// ---------------------------------------------------------------------------
extern "C" void kernel_launch(void* const* d_in, const int* in_sizes, int n_in,
                              void* d_out, int out_size, void* d_ws, size_t ws_size,
                              hipStream_t stream) {
    const float* x    = (const float*)d_in[0];
    const float* w    = (const float*)d_in[1];
    const float* thrp = (const float*)d_in[2];
    float* out = (float*)d_out;

    const size_t elems = (size_t)M_DIM * K_DIM;
    if (ws_size >= 2 * elems * sizeof(unsigned short)) {
        unsigned short* Ab = (unsigned short*)d_ws;
        unsigned short* Bb = Ab + elems;
        const int n8 = (int)(elems / 8);
        prune_cvt2<<<2048, 256, 0, stream>>>(x, w, Ab, Bb, thrp, n8);
        gemm_bigacc<<<dim3(256), dim3(256), 0, stream>>>(Ab, Bb, out);
    } else {
        dim3 grid(N_DIM / 32, M_DIM / 32), blk(32, 32);
        gemm_f32_fallback<<<grid, blk, 0, stream>>>(x, w, out, thrp);
    }
}

// Round 12
// 177.478 us; speedup vs baseline: 1.6039x; 1.6039x over previous
//
#include <hip/hip_runtime.h>
#include <hip/hip_bf16.h>

#define M_DIM 4096
#define N_DIM 4096
#define K_DIM 4096

typedef __attribute__((ext_vector_type(8))) __bf16 bf16x8;
typedef __attribute__((ext_vector_type(8))) short short8;
typedef __attribute__((ext_vector_type(8))) unsigned short ushort8;
typedef __attribute__((ext_vector_type(4))) float f32x4;

__device__ __forceinline__ bf16x8 ld8(const unsigned short* p) {
    short8 r = *reinterpret_cast<const short8*>(p);
    return __builtin_bit_cast(bf16x8, r);
}

// prune (|f|>thr keep, else 0) + fp32->bf16 on 8 floats; thr=-1 keeps all
__device__ __forceinline__ ushort8 cvt8(float4 a, float4 b, float thr) {
    float v[8] = {a.x, a.y, a.z, a.w, b.x, b.y, b.z, b.w};
    ushort8 o;
#pragma unroll
    for (int e = 0; e < 8; ++e) {
        float f = v[e];
        f = (fabsf(f) > thr) ? f : 0.0f;
        __hip_bfloat16 h = __float2bfloat16(f);
        o[e] = *reinterpret_cast<unsigned short*>(&h);
    }
    return o;
}

// ---------------------------------------------------------------------------
// FUSED prune+cvt+GEMM: C = prune(X) * W^T, all fp32 inputs, f32 output.
// 256x256 tile, BK=64, 8 waves (2Mx4N), 16x16x32 MFMA, R6 phase skeleton.
//
// Staging is reg-based (global fp32 -> prune/cvt in VGPR -> ds_write_b128),
// replacing the separate conversion kernel. Per thread per K-tile:
//   A: 8 float4 loads -> 4 ushort8 writes ; B: same. Issue/write schedule:
//   ph0: issue A k0,k1   ph1: write A k0,k1; issue A k2,k3
//   ph2: write A k2,k3; issue B k0..k3      ph3: write B k0..k3
// Loads are consumed ~1 phase (~1000 cyc) after issue -> HBM/L3 latency
// hidden; data-dep vmcnt is compiler-managed.
//
// Sync: ONE s_waitcnt lgkmcnt(0) + s_barrier per K-tile (end-ph3).
// WAR audit (single barrier suffices):
//   A-writes @ph1/ph2(t) -> AbN; old AbN content (tile t-1) last read @ph2(t-1),
//     separated by barrier(t-1).
//   B-writes @ph3(t) -> BbN; old BbN content last read @ph0(t-1). Separated.
//   New content first read @ph0(t+1), after lgkmcnt(0)+barrier. OK.
//
// LDS per buffer: A[256][64], B[256][64] bf16, slot-swizzled:
//   element(row, col c) at row*64 + 8*((c>>3) ^ (row&7)) + (c&7)
// ---------------------------------------------------------------------------
__global__ __launch_bounds__(512, 2) void gemm_fused(
        const float* __restrict__ X,
        const float* __restrict__ W,
        const float* __restrict__ thrp,
        float* __restrict__ C) {
    __shared__ __align__(16) unsigned short lds[65536];  // 128 KB

    const float thr = thrp[0];
    const int tid  = threadIdx.x;
    const int lane = tid & 63;
    const int wid  = tid >> 6;
    const int wr   = wid >> 2;   // 0..1 : 128-row strip
    const int wc   = wid & 3;    // 0..3 : 64-col strip

    // XCD-aware bijective swizzle (256 blocks / 8 XCDs)
    const int bid = blockIdx.x;
    const int swz = (bid & 7) * 32 + (bid >> 3);
    const int bm = (swz >> 4) * 256;
    const int bn = (swz & 15) * 256;

    // staging assignment: slot sx (8 cols), rows rb + 64k (k=0..3)
    const int sx = tid & 7;
    const int rb = tid >> 3;                 // 0..63
    const float* xbase = X + (size_t)(bm + rb) * K_DIM + sx * 8;
    const float* wbase = W + (size_t)(bn + rb) * K_DIM + sx * 8;
    const int dstoff = rb * 64 + 8 * (sx ^ (rb & 7));   // + k*4096 elems

#define LDF4(base, kn, k, half) \
    (*reinterpret_cast<const float4*>((base) + (kn) + (size_t)(k) * 64 * K_DIM + 4 * (half)))
#define STW(dstb, k, u) \
    (*reinterpret_cast<ushort8*>((dstb) + dstoff + 4096 * (k)) = (u))

    // fragment read offsets (swizzle slot is thread-constant)
    const int fr  = lane & 15;
    const int kq4 = lane >> 4;
    const int rowOffA = (wr * 128 + fr) * 64;
    const int rowOffB = (wc * 64 + fr) * 64;
    const int sk0 = 8 * ((kq4    ) ^ (fr & 7));
    const int sk1 = 8 * ((kq4 + 4) ^ (fr & 7));

    f32x4 acc[8][4] = {};
    bf16x8 bfr[4][2];

#define MFMA16(q, A00, A10, A01, A11)                                                              \
    __builtin_amdgcn_s_setprio(1);                                                                 \
    _Pragma("unroll")                                                                              \
    for (int n = 0; n < 4; ++n) {                                                                  \
        acc[2*(q)][n]   = __builtin_amdgcn_mfma_f32_16x16x32_bf16(A00, bfr[n][0], acc[2*(q)][n], 0, 0, 0);   \
        acc[2*(q)+1][n] = __builtin_amdgcn_mfma_f32_16x16x32_bf16(A10, bfr[n][0], acc[2*(q)+1][n], 0, 0, 0); \
    }                                                                                              \
    _Pragma("unroll")                                                                              \
    for (int n = 0; n < 4; ++n) {                                                                  \
        acc[2*(q)][n]   = __builtin_amdgcn_mfma_f32_16x16x32_bf16(A01, bfr[n][1], acc[2*(q)][n], 0, 0, 0);   \
        acc[2*(q)+1][n] = __builtin_amdgcn_mfma_f32_16x16x32_bf16(A11, bfr[n][1], acc[2*(q)+1][n], 0, 0, 0); \
    }                                                                                              \
    __builtin_amdgcn_s_setprio(0);

    // One K-tile: reads from (Ab,Bb); stages tile t+1 (K-offset kn) into
    // (AbN,BbN) via reg prune/cvt. One barrier per tile at end-ph3.
#define TILE_BODY(Ab, Bb, AbN, BbN, kn)                                                            \
    {                                                                                              \
        /* ph0: read B(t)x8 + A-j0 + A-j1; issue A(t+1) k0,k1; MFMA j0 */                          \
        _Pragma("unroll")                                                                          \
        for (int n = 0; n < 4; ++n) {                                                              \
            bfr[n][0] = ld8((Bb) + rowOffB + n * 1024 + sk0);                                      \
            bfr[n][1] = ld8((Bb) + rowOffB + n * 1024 + sk1);                                      \
        }                                                                                          \
        bf16x8 p00 = ld8((Ab) + rowOffA + 0 * 1024 + sk0);                                         \
        bf16x8 p10 = ld8((Ab) + rowOffA + 1 * 1024 + sk0);                                         \
        bf16x8 p01 = ld8((Ab) + rowOffA + 0 * 1024 + sk1);                                         \
        bf16x8 p11 = ld8((Ab) + rowOffA + 1 * 1024 + sk1);                                         \
        bf16x8 q00 = ld8((Ab) + rowOffA + 2 * 1024 + sk0);                                         \
        bf16x8 q10 = ld8((Ab) + rowOffA + 3 * 1024 + sk0);                                         \
        bf16x8 q01 = ld8((Ab) + rowOffA + 2 * 1024 + sk1);                                         \
        bf16x8 q11 = ld8((Ab) + rowOffA + 3 * 1024 + sk1);                                         \
        float4 a0l = LDF4(xbase, kn, 0, 0), a0h = LDF4(xbase, kn, 0, 1);                           \
        float4 a1l = LDF4(xbase, kn, 1, 0), a1h = LDF4(xbase, kn, 1, 1);                           \
        MFMA16(0, p00, p10, p01, p11);                                                             \
        /* ph1: read A-j2; write A k0,k1; issue A k2,k3; MFMA j1 */                                \
        bf16x8 r00 = ld8((Ab) + rowOffA + 4 * 1024 + sk0);                                         \
        bf16x8 r10 = ld8((Ab) + rowOffA + 5 * 1024 + sk0);                                         \
        bf16x8 r01 = ld8((Ab) + rowOffA + 4 * 1024 + sk1);                                         \
        bf16x8 r11 = ld8((Ab) + rowOffA + 5 * 1024 + sk1);                                         \
        STW((AbN), 0, cvt8(a0l, a0h, thr));                                                        \
        STW((AbN), 1, cvt8(a1l, a1h, thr));                                                        \
        float4 a2l = LDF4(xbase, kn, 2, 0), a2h = LDF4(xbase, kn, 2, 1);                           \
        float4 a3l = LDF4(xbase, kn, 3, 0), a3h = LDF4(xbase, kn, 3, 1);                           \
        MFMA16(1, q00, q10, q01, q11);                                                             \
        /* ph2: read A-j3; write A k2,k3; issue B k0..k3; MFMA j2 */                               \
        bf16x8 s00 = ld8((Ab) + rowOffA + 6 * 1024 + sk0);                                         \
        bf16x8 s10 = ld8((Ab) + rowOffA + 7 * 1024 + sk0);                                         \
        bf16x8 s01 = ld8((Ab) + rowOffA + 6 * 1024 + sk1);                                         \
        bf16x8 s11 = ld8((Ab) + rowOffA + 7 * 1024 + sk1);                                         \
        STW((AbN), 2, cvt8(a2l, a2h, thr));                                                        \
        STW((AbN), 3, cvt8(a3l, a3h, thr));                                                        \
        float4 b0l = LDF4(wbase, kn, 0, 0), b0h = LDF4(wbase, kn, 0, 1);                           \
        float4 b1l = LDF4(wbase, kn, 1, 0), b1h = LDF4(wbase, kn, 1, 1);                           \
        float4 b2l = LDF4(wbase, kn, 2, 0), b2h = LDF4(wbase, kn, 2, 1);                           \
        float4 b3l = LDF4(wbase, kn, 3, 0), b3h = LDF4(wbase, kn, 3, 1);                           \
        MFMA16(2, r00, r10, r01, r11);                                                             \
        /* ph3: write B k0..k3; MFMA j3; drain + barrier */                                        \
        STW((BbN), 0, cvt8(b0l, b0h, -1.0f));                                                      \
        STW((BbN), 1, cvt8(b1l, b1h, -1.0f));                                                      \
        STW((BbN), 2, cvt8(b2l, b2h, -1.0f));                                                      \
        STW((BbN), 3, cvt8(b3l, b3h, -1.0f));                                                      \
        MFMA16(3, s00, s10, s01, s11);                                                             \
        asm volatile("s_waitcnt lgkmcnt(0)" ::: "memory");                                         \
        asm volatile("s_barrier" ::: "memory");                                                    \
    }

    // compile-time buffer bases
    unsigned short* A0 = lds;
    unsigned short* A1 = lds + 16384;
    unsigned short* B0 = lds + 32768;
    unsigned short* B1 = lds + 49152;

    // ---- prologue: stage tile 0 into buf0 (reg prune/cvt path)
    {
        float4 a0l = LDF4(xbase, 0, 0, 0), a0h = LDF4(xbase, 0, 0, 1);
        float4 a1l = LDF4(xbase, 0, 1, 0), a1h = LDF4(xbase, 0, 1, 1);
        float4 a2l = LDF4(xbase, 0, 2, 0), a2h = LDF4(xbase, 0, 2, 1);
        float4 a3l = LDF4(xbase, 0, 3, 0), a3h = LDF4(xbase, 0, 3, 1);
        float4 b0l = LDF4(wbase, 0, 0, 0), b0h = LDF4(wbase, 0, 0, 1);
        float4 b1l = LDF4(wbase, 0, 1, 0), b1h = LDF4(wbase, 0, 1, 1);
        float4 b2l = LDF4(wbase, 0, 2, 0), b2h = LDF4(wbase, 0, 2, 1);
        float4 b3l = LDF4(wbase, 0, 3, 0), b3h = LDF4(wbase, 0, 3, 1);
        STW(A0, 0, cvt8(a0l, a0h, thr));
        STW(A0, 1, cvt8(a1l, a1h, thr));
        STW(A0, 2, cvt8(a2l, a2h, thr));
        STW(A0, 3, cvt8(a3l, a3h, thr));
        STW(B0, 0, cvt8(b0l, b0h, -1.0f));
        STW(B0, 1, cvt8(b1l, b1h, -1.0f));
        STW(B0, 2, cvt8(b2l, b2h, -1.0f));
        STW(B0, 3, cvt8(b3l, b3h, -1.0f));
        asm volatile("s_waitcnt lgkmcnt(0)" ::: "memory");
        asm volatile("s_barrier" ::: "memory");
    }

    for (int t = 0; t < 64; t += 2) {
        const int kn0 = (t + 1) * 64;                     // t+1 <= 63, never clamps
        const int kn1 = (t + 2 < 64 ? t + 2 : 63) * 64;   // clamp: tail stage is dead
        TILE_BODY(A0, B0, A1, B1, kn0);   // even: read buf0, stage t+1 -> buf1
        TILE_BODY(A1, B1, A0, B0, kn1);   // odd:  read buf1, stage t+2 -> buf0
    }

    // C/D layout (m89): col = lane&15, row = (lane>>4)*4 + j
    const int crow = bm + wr * 128 + kq4 * 4;
    const int ccol = bn + wc * 64 + fr;
#pragma unroll
    for (int m = 0; m < 8; ++m)
#pragma unroll
        for (int n = 0; n < 4; ++n)
#pragma unroll
            for (int j = 0; j < 4; ++j)
                C[(size_t)(crow + m * 16 + j) * N_DIM + ccol + n * 16] = acc[m][n][j];
}

// ---------------------------------------------------------------------------
extern "C" void kernel_launch(void* const* d_in, const int* in_sizes, int n_in,
                              void* d_out, int out_size, void* d_ws, size_t ws_size,
                              hipStream_t stream) {
    const float* x    = (const float*)d_in[0];
    const float* w    = (const float*)d_in[1];
    const float* thrp = (const float*)d_in[2];
    float* out = (float*)d_out;
    (void)d_ws; (void)ws_size;

    gemm_fused<<<dim3(256), dim3(512), 0, stream>>>(x, w, thrp, out);
}

// Round 13
// 142.537 us; speedup vs baseline: 1.9971x; 1.2451x over previous
//
#include <hip/hip_runtime.h>
#include <hip/hip_bf16.h>

#define M_DIM 4096
#define N_DIM 4096
#define K_DIM 4096

typedef __attribute__((ext_vector_type(8))) __bf16 bf16x8;
typedef __attribute__((ext_vector_type(8))) short short8;
typedef __attribute__((ext_vector_type(8))) unsigned short ushort8;
typedef __attribute__((ext_vector_type(4))) float f32x4;

// async global->LDS, 16B/lane (m104: dest = wave-uniform base + lane*16)
__device__ __forceinline__ void gload_lds16(const void* g, void* l) {
    __builtin_amdgcn_global_load_lds(
        (const __attribute__((address_space(1))) void*)g,
        (__attribute__((address_space(3))) void*)l,
        16, 0, 0);
}

__device__ __forceinline__ bf16x8 ld8(const unsigned short* p) {
    short8 r = *reinterpret_cast<const short8*>(p);
    return __builtin_bit_cast(bf16x8, r);
}

// ---------------------------------------------------------------------------
// fused fp32->bf16 conversion: x (pruned) and w (unpruned) in ONE launch
// ---------------------------------------------------------------------------
__global__ void prune_cvt2(const float* __restrict__ x,
                           const float* __restrict__ w,
                           unsigned short* __restrict__ xb,
                           unsigned short* __restrict__ wb,
                           const float* __restrict__ thrp, int n8) {
    const float thr = thrp[0];
    const int stride = gridDim.x * blockDim.x;
    const int total = 2 * n8;
    for (int idx = blockIdx.x * blockDim.x + threadIdx.x; idx < total; idx += stride) {
        const bool isx = idx < n8;
        const int j = isx ? idx : idx - n8;
        const float* src = isx ? x : w;
        unsigned short* dst = isx ? xb : wb;
        const float te = isx ? thr : -1.0f;   // |v| > -1 always true -> keep all
        const float4* p = reinterpret_cast<const float4*>(src) + 2 * (size_t)j;
        float4 v0 = p[0];
        float4 v1 = p[1];
        float v[8] = {v0.x, v0.y, v0.z, v0.w, v1.x, v1.y, v1.z, v1.w};
        ushort8 o;
#pragma unroll
        for (int e = 0; e < 8; ++e) {
            float f = v[e];
            f = (fabsf(f) > te) ? f : 0.0f;   // prune in fp32 (exact predicate)
            __hip_bfloat16 hh = __float2bfloat16(f);
            o[e] = *reinterpret_cast<unsigned short*>(&hh);
        }
        *reinterpret_cast<ushort8*>(dst + 8 * (size_t)j) = o;
    }
}

// ---------------------------------------------------------------------------
// C = A * B^T, 256x256 tile, BK=64, 8 waves, 16x16x32 MFMA, R6 skeleton with
// ONE barrier per K-tile (end-ph2): all 8 stages issue at ph0, the single
// lgkmcnt(0)+vmcnt(0)+s_barrier at end-ph2 lands them (~2 phases of slack,
// >HBM latency), and waves drift freely across ph3->ph0->ph1->ph2 so LDS
// read-storms of drifted waves overlap other waves' MFMA clusters.
//
// Hazard audit (1 barrier suffices):
//  RAW: tile t's LDS content staged @ph0(t-1), drained+published @end-ph2(t-1)
//       barrier; first read @ph3(t-1) (p-set from nxt) — after that barrier. OK
//  WAR: stage-writes @ph0(t) target buf nxt(t)=cur(t-1); last reads of that
//       content are @ph2(t-1) (s-frags), drained by lgkmcnt(0) before the
//       end-ph2(t-1) barrier; writes are after it. OK
//  B-frags are read same-phase @ph0 (champion-R6 behavior, proven).
//
// LDS per buffer: A[256][64], B[256][64], slot-swizzled:
//   element(row, logical col c) at row*64 + 8*((c>>3) ^ (row&7)) + (c&7)
// ---------------------------------------------------------------------------
__global__ __launch_bounds__(512, 2) void gemm_8phase(
        const unsigned short* __restrict__ A,
        const unsigned short* __restrict__ B,
        float* __restrict__ C) {
    __shared__ __align__(16) unsigned short lds[65536];  // 128 KB

    const int tid  = threadIdx.x;
    const int lane = tid & 63;
    const int wid  = tid >> 6;
    const int wr   = wid >> 2;   // 0..1 : 128-row strip
    const int wc   = wid & 3;    // 0..3 : 64-col strip

    // XCD-aware bijective swizzle (256 blocks / 8 XCDs)
    const int bid = blockIdx.x;
    const int swz = (bid & 7) * 32 + (bid >> 3);
    const int bm = (swz >> 4) * 256;
    const int bn = (swz & 15) * 256;

    // staging: A-half ah staged by threads [ah*256, +256); load j = rows [32j,+32)
    const int g  = tid & 255;
    const int ah = tid >> 8;
    const int arow = bm + ah * 128 + (g >> 3);
    const int acol = 8 * ((g & 7) ^ ((g >> 3) & 7));      // pre-swizzled source col
    const unsigned short* Asrc = A + (size_t)arow * K_DIM + acol;
    const int AdstE = ah * 8192 + g * 8;

    const int h = lane + 64 * wr;
    const int brow = bn + wc * 64 + (h >> 3);
    const int bcol = 8 * ((h & 7) ^ ((h >> 3) & 7));
    const unsigned short* Bsrc = B + (size_t)brow * K_DIM + bcol;
    const int BdstE = wc * 4096 + h * 8;

#define SA(dstb, j, kg) gload_lds16(Asrc + (size_t)(32*(j))*K_DIM + (kg), (dstb) + AdstE + 2048*(j))
#define SB(dstb, j, kg) gload_lds16(Bsrc + (size_t)(16*(j))*K_DIM + (kg), (dstb) + BdstE + 1024*(j))

    // fragment read offsets (row&7 == fr&7 -> swizzle slot is thread-constant)
    const int fr  = lane & 15;
    const int kq4 = lane >> 4;
    const int rowOffA = (wr * 128 + fr) * 64;
    const int rowOffB = (wc * 64 + fr) * 64;
    const int sk0 = 8 * ((kq4    ) ^ (fr & 7));
    const int sk1 = 8 * ((kq4 + 4) ^ (fr & 7));

    f32x4 acc[8][4] = {};

    bf16x8 bfr[4][2];
#define MFMA16(q, A00, A10, A01, A11)                                                              \
    __builtin_amdgcn_s_setprio(1);                                                                 \
    _Pragma("unroll")                                                                              \
    for (int n = 0; n < 4; ++n) {                                                                  \
        acc[2*(q)][n]   = __builtin_amdgcn_mfma_f32_16x16x32_bf16(A00, bfr[n][0], acc[2*(q)][n], 0, 0, 0);   \
        acc[2*(q)+1][n] = __builtin_amdgcn_mfma_f32_16x16x32_bf16(A10, bfr[n][0], acc[2*(q)+1][n], 0, 0, 0); \
    }                                                                                              \
    _Pragma("unroll")                                                                              \
    for (int n = 0; n < 4; ++n) {                                                                  \
        acc[2*(q)][n]   = __builtin_amdgcn_mfma_f32_16x16x32_bf16(A01, bfr[n][1], acc[2*(q)][n], 0, 0, 0);   \
        acc[2*(q)+1][n] = __builtin_amdgcn_mfma_f32_16x16x32_bf16(A11, bfr[n][1], acc[2*(q)+1][n], 0, 0, 0); \
    }                                                                                              \
    __builtin_amdgcn_s_setprio(0);

    // One K-tile body: reads (Ab,Bb); ALL stages for tile t+1 at ph0; ONE
    // lgkmcnt(0)+vmcnt(0)+barrier at end-ph2; ph3 pre-reads A(t+1)-j0.
#define TILE_BODY(Ab, Bb, AbN, BbN, kn)                                                            \
    {                                                                                              \
        /* ph0: MFMA j0 (p-set); read B(t)x8 + A(t)-j1; stage ALL 8 for t+1 */                     \
        _Pragma("unroll")                                                                          \
        for (int n = 0; n < 4; ++n) {                                                              \
            bfr[n][0] = ld8((Bb) + rowOffB + n * 1024 + sk0);                                      \
            bfr[n][1] = ld8((Bb) + rowOffB + n * 1024 + sk1);                                      \
        }                                                                                          \
        bf16x8 q00 = ld8((Ab) + rowOffA + 2 * 1024 + sk0);                                         \
        bf16x8 q10 = ld8((Ab) + rowOffA + 3 * 1024 + sk0);                                         \
        bf16x8 q01 = ld8((Ab) + rowOffA + 2 * 1024 + sk1);                                         \
        bf16x8 q11 = ld8((Ab) + rowOffA + 3 * 1024 + sk1);                                         \
        SB((BbN), 0, (kn)); SB((BbN), 1, (kn)); SB((BbN), 2, (kn)); SB((BbN), 3, (kn));            \
        SA((AbN), 0, (kn)); SA((AbN), 1, (kn)); SA((AbN), 2, (kn)); SA((AbN), 3, (kn));            \
        MFMA16(0, p00, p10, p01, p11);                                                             \
        /* ph1: MFMA j1 (q-set); read A(t)-j2 */                                                   \
        bf16x8 r00 = ld8((Ab) + rowOffA + 4 * 1024 + sk0);                                         \
        bf16x8 r10 = ld8((Ab) + rowOffA + 5 * 1024 + sk0);                                         \
        bf16x8 r01 = ld8((Ab) + rowOffA + 4 * 1024 + sk1);                                         \
        bf16x8 r11 = ld8((Ab) + rowOffA + 5 * 1024 + sk1);                                         \
        MFMA16(1, q00, q10, q01, q11);                                                             \
        /* ph2: MFMA j2 (r-set); read A(t)-j3; SINGLE sync point */                                \
        bf16x8 s00 = ld8((Ab) + rowOffA + 6 * 1024 + sk0);                                         \
        bf16x8 s10 = ld8((Ab) + rowOffA + 7 * 1024 + sk0);                                         \
        bf16x8 s01 = ld8((Ab) + rowOffA + 6 * 1024 + sk1);                                         \
        bf16x8 s11 = ld8((Ab) + rowOffA + 7 * 1024 + sk1);                                         \
        MFMA16(2, r00, r10, r01, r11);                                                             \
        asm volatile("s_waitcnt lgkmcnt(0) vmcnt(0)" ::: "memory");                                \
        asm volatile("s_barrier" ::: "memory");                                                    \
        /* ph3: MFMA j3 (s-set); pre-read A(t+1)-j0 from next buf */                               \
        p00 = ld8((AbN) + rowOffA + 0 * 1024 + sk0);                                               \
        p10 = ld8((AbN) + rowOffA + 1 * 1024 + sk0);                                               \
        p01 = ld8((AbN) + rowOffA + 0 * 1024 + sk1);                                               \
        p11 = ld8((AbN) + rowOffA + 1 * 1024 + sk1);                                               \
        MFMA16(3, s00, s10, s01, s11);                                                             \
    }

    // compile-time buffer bases
    unsigned short* A0 = lds;
    unsigned short* A1 = lds + 16384;
    unsigned short* B0 = lds + 32768;
    unsigned short* B1 = lds + 49152;

    // ---- prologue: stage tile0 into buf0; land everything; pre-read j0 frags
    SB(B0, 0, 0); SB(B0, 1, 0); SB(B0, 2, 0); SB(B0, 3, 0);
    SA(A0, 0, 0); SA(A0, 1, 0); SA(A0, 2, 0); SA(A0, 3, 0);
    asm volatile("s_waitcnt vmcnt(0)" ::: "memory");
    asm volatile("s_barrier" ::: "memory");

    bf16x8 p00 = ld8(A0 + rowOffA + 0 * 1024 + sk0);
    bf16x8 p10 = ld8(A0 + rowOffA + 1 * 1024 + sk0);
    bf16x8 p01 = ld8(A0 + rowOffA + 0 * 1024 + sk1);
    bf16x8 p11 = ld8(A0 + rowOffA + 1 * 1024 + sk1);

    for (int t = 0; t < 64; t += 2) {
        const int kn0 = (t + 1) * 64;                     // t+1 <= 63, never clamps
        const int kn1 = (t + 2 < 64 ? t + 2 : 63) * 64;   // clamp: tail stage is dead
        TILE_BODY(A0, B0, A1, B1, kn0);   // even tile: read buf0, stage buf1
        TILE_BODY(A1, B1, A0, B0, kn1);   // odd tile:  read buf1, stage buf0
    }

    asm volatile("s_waitcnt vmcnt(0)" ::: "memory");  // drain dead tail stages

    // C/D layout (m89): col = lane&15, row = (lane>>4)*4 + j
    const int crow = bm + wr * 128 + kq4 * 4;
    const int ccol = bn + wc * 64 + fr;
#pragma unroll
    for (int m = 0; m < 8; ++m)
#pragma unroll
        for (int n = 0; n < 4; ++n)
#pragma unroll
            for (int j = 0; j < 4; ++j)
                C[(size_t)(crow + m * 16 + j) * N_DIM + ccol + n * 16] = acc[m][n][j];
}

// ---------------------------------------------------------------------------
// fp32 fallback (only if ws too small)
// ---------------------------------------------------------------------------
__global__ void gemm_f32_fallback(const float* __restrict__ A,
                                  const float* __restrict__ B,
                                  float* __restrict__ C,
                                  const float* __restrict__ thrp) {
    __shared__ float As[32][33];
    __shared__ float Bs[32][33];
    const float thr = thrp[0];
    const int tx = threadIdx.x, ty = threadIdx.y;
    const int row = blockIdx.y * 32 + ty;
    float acc = 0.0f;
    for (int k0 = 0; k0 < K_DIM; k0 += 32) {
        float a = A[(size_t)row * K_DIM + k0 + tx];
        As[ty][tx] = (fabsf(a) > thr) ? a : 0.0f;
        Bs[ty][tx] = B[(size_t)(blockIdx.x * 32 + ty) * K_DIM + k0 + tx];
        __syncthreads();
#pragma unroll 8
        for (int kk = 0; kk < 32; ++kk)
            acc += As[ty][kk] * Bs[tx][kk];
        __syncthreads();
    }
    C[(size_t)row * N_DIM + blockIdx.x * 32 + tx] = acc;
}

// ---------------------------------------------------------------------------
extern "C" void kernel_launch(void* const* d_in, const int* in_sizes, int n_in,
                              void* d_out, int out_size, void* d_ws, size_t ws_size,
                              hipStream_t stream) {
    const float* x    = (const float*)d_in[0];
    const float* w    = (const float*)d_in[1];
    const float* thrp = (const float*)d_in[2];
    float* out = (float*)d_out;

    const size_t elems = (size_t)M_DIM * K_DIM;
    if (ws_size >= 2 * elems * sizeof(unsigned short)) {
        unsigned short* Ab = (unsigned short*)d_ws;
        unsigned short* Bb = Ab + elems;
        const int n8 = (int)(elems / 8);
        prune_cvt2<<<2048, 256, 0, stream>>>(x, w, Ab, Bb, thrp, n8);
        gemm_8phase<<<dim3(256), dim3(512), 0, stream>>>(Ab, Bb, out);
    } else {
        dim3 grid(N_DIM / 32, M_DIM / 32), blk(32, 32);
        gemm_f32_fallback<<<grid, blk, 0, stream>>>(x, w, out, thrp);
    }
}